// Round 2
// baseline (380.417 us; speedup 1.0000x reference)
//
#include <hip/hip_runtime.h>

// IntDVF: scaling-and-squaring integration of a stationary velocity field.
// ddf = dvf / 2^7; repeat 7x: ddf = ddf + trilerp(ddf, grid + ddf)
// Volume: (B=2, D=128, H=128, W=128, C=3) float32, coords clamped to [0,127].
//
// Layout trick: intermediates are stored split as
//   float2 xy[NVOX]  (channels 0,1)   -- 8B-aligned gathers (dwordx2)
//   float  z [NVOX]  (channel 2)      -- 4B gathers
// which cuts the wave-level L1 line footprint of the 8-corner gather ~3x
// vs AoS-12B (R1 was L1/TA line-throughput bound at 49.6us/step).

#define M_   (1 << 21)          // 128^3 voxels per batch
#define NVOX (1 << 22)          // 2 batches

// ---------- pass 0: scale + transpose (AoS12 -> split planes), 4 vox/thread ----------
__global__ __launch_bounds__(256) void t_kernel(const float* __restrict__ src,
                                                float2* __restrict__ dxy,
                                                float* __restrict__ dz) {
    const int t = blockIdx.x * blockDim.x + threadIdx.x;   // 0 .. NVOX/4-1
    const float s = 1.0f / 128.0f;
    const float4* s4 = (const float4*)src;
    const float4 a = s4[3 * t + 0];
    const float4 b = s4[3 * t + 1];
    const float4 c = s4[3 * t + 2];
    // voxels v..v+3, channels (c0,c1,c2):
    // v0:(a.x,a.y,a.z) v1:(a.w,b.x,b.y) v2:(b.z,b.w,c.x) v3:(c.y,c.z,c.w)
    float4* dxy4 = (float4*)dxy;
    dxy4[2 * t + 0] = make_float4(a.x * s, a.y * s, a.w * s, b.x * s);
    dxy4[2 * t + 1] = make_float4(b.z * s, b.w * s, c.y * s, c.z * s);
    ((float4*)dz)[t] = make_float4(a.z * s, b.y * s, c.x * s, c.w * s);
}

// ---------- warp step: split -> split (or AoS on final) ----------
template <bool DST_AOS>
__global__ __launch_bounds__(256) void step_k(const float2* __restrict__ sxy,
                                              const float* __restrict__ sz,
                                              float2* __restrict__ dxy,
                                              float* __restrict__ dz,
                                              float* __restrict__ daos) {
    const int idx = blockIdx.x * blockDim.x + threadIdx.x;
    const int x = idx & 127;
    const int y = (idx >> 7) & 127;
    const int z = (idx >> 14) & 127;
    const int bb = idx & (M_);           // batch base (bit 21)

    const float2 cxy = sxy[idx];
    const float  czc = sz[idx];
    const float v0 = cxy.x;              // D (z) displacement
    const float v1 = cxy.y;              // H (y)
    const float v2 = czc;                // W (x)

    const float cz = fminf(fmaxf((float)z + v0, 0.0f), 127.0f);
    const float cy = fminf(fmaxf((float)y + v1, 0.0f), 127.0f);
    const float cx = fminf(fmaxf((float)x + v2, 0.0f), 127.0f);

    const float fz = floorf(cz), fy = floorf(cy), fx = floorf(cx);
    const float wz = cz - fz, wy = cy - fy, wx = cx - fx;
    const int i0z = (int)fz, i0y = (int)fy, i0x = (int)fx;
    const int i1z = min(i0z + 1, 127);
    const int i1y = min(i0y + 1, 127);
    const int i1x = min(i0x + 1, 127);
    const float wz0 = 1.0f - wz, wy0 = 1.0f - wy, wx0 = 1.0f - wx;

    float o0 = 0.0f, o1 = 0.0f, o2 = 0.0f;
    #pragma unroll
    for (int b0 = 0; b0 < 2; ++b0) {
        const int   iz  = (b0 ? i1z : i0z) << 14;
        const float wwz = b0 ? wz : wz0;
        #pragma unroll
        for (int b1 = 0; b1 < 2; ++b1) {
            const int   iy   = (b1 ? i1y : i0y) << 7;
            const float wwzy = wwz * (b1 ? wy : wy0);
            #pragma unroll
            for (int b2 = 0; b2 < 2; ++b2) {
                const int ix = b2 ? i1x : i0x;
                const float wt = wwzy * (b2 ? wx : wx0);
                const int vox = bb + (iz | iy | ix);
                const float2 q = sxy[vox];
                const float qz = sz[vox];
                o0 += wt * q.x;
                o1 += wt * q.y;
                o2 += wt * qz;
            }
        }
    }

    const float r0 = v0 + o0, r1 = v1 + o1, r2 = v2 + o2;
    if (DST_AOS) {
        float* d = daos + (size_t)idx * 3;
        d[0] = r0; d[1] = r1; d[2] = r2;
    } else {
        dxy[idx] = make_float2(r0, r1);
        dz[idx] = r2;
    }
}

extern "C" void kernel_launch(void* const* d_in, const int* in_sizes, int n_in,
                              void* d_out, int out_size, void* d_ws, size_t ws_size,
                              hipStream_t stream) {
    const float* dvf = (const float*)d_in[0];
    float* out = (float*)d_out;
    float* ws  = (float*)d_ws;

    // split-plane views inside each 50.3MB buffer: float2 xy[NVOX] then float z[NVOX]
    float2* ws_xy  = (float2*)ws;
    float*  ws_z   = ws + (size_t)NVOX * 2;
    float2* out_xy = (float2*)out;
    float*  out_z  = out + (size_t)NVOX * 2;

    const dim3 blk(256);
    const dim3 grd(NVOX / 256);
    const dim3 grd4(NVOX / 4 / 256);

    // scale+transpose, then 7 steps ping-ponging ws <-> out, final AoS into out
    t_kernel<<<grd4, blk, 0, stream>>>(dvf, ws_xy, ws_z);
    step_k<false><<<grd, blk, 0, stream>>>(ws_xy,  ws_z,  out_xy, out_z, nullptr); // s1
    step_k<false><<<grd, blk, 0, stream>>>(out_xy, out_z, ws_xy,  ws_z,  nullptr); // s2
    step_k<false><<<grd, blk, 0, stream>>>(ws_xy,  ws_z,  out_xy, out_z, nullptr); // s3
    step_k<false><<<grd, blk, 0, stream>>>(out_xy, out_z, ws_xy,  ws_z,  nullptr); // s4
    step_k<false><<<grd, blk, 0, stream>>>(ws_xy,  ws_z,  out_xy, out_z, nullptr); // s5
    step_k<false><<<grd, blk, 0, stream>>>(out_xy, out_z, ws_xy,  ws_z,  nullptr); // s6
    step_k<true> <<<grd, blk, 0, stream>>>(ws_xy,  ws_z,  nullptr, nullptr, out);  // s7
}

// Round 3
// 177.114 us; speedup vs baseline: 2.1479x; 2.1479x over previous
//
#include <hip/hip_runtime.h>

// IntDVF: scaling-and-squaring integration of a stationary velocity field.
// ddf = dvf / 2^7; repeat 7x: ddf = ddf + trilerp(ddf, grid + ddf)
// Volume: (B=2, D=128, H=128, W=128, C=3) float32, coords clamped to [0,127].
//
// R1/R2 showed the kernel is bound by L1 line-lookup throughput of the
// 8-corner gathers (white-noise displacements -> ~1 distinct line per lane
// per gather instr). Fix: store intermediates as fp16 padded to 8B/voxel so
// each row's x-pair (2 corners x 3 channels) is ONE 16B dwordx4 gather ->
// 4 gather instrs/voxel instead of 8 dwordx3. fp16 error bound ~0.04 << 6.7e-2.

#define M_   (1 << 21)          // 128^3 voxels per batch
#define NVOX (1 << 22)          // 2 batches

typedef _Float16 h4 __attribute__((ext_vector_type(4)));
typedef _Float16 h8 __attribute__((ext_vector_type(8)));
struct __attribute__((packed, aligned(8))) H8U { h8 v; };   // 16B load, 8B-aligned

// ---------- pass 0: scale + pack (f32 AoS12 -> fp16 8B/voxel), 4 vox/thread ----------
__global__ __launch_bounds__(256) void t_kernel(const float* __restrict__ src,
                                                h4* __restrict__ dst) {
    const int t = blockIdx.x * blockDim.x + threadIdx.x;   // 0 .. NVOX/4-1
    const float s = 1.0f / 128.0f;
    const float4* s4 = (const float4*)src;
    const float4 a = s4[3 * t + 0];
    const float4 b = s4[3 * t + 1];
    const float4 c = s4[3 * t + 2];
    // voxels v..v+3: v0:(a.x,a.y,a.z) v1:(a.w,b.x,b.y) v2:(b.z,b.w,c.x) v3:(c.y,c.z,c.w)
    h4 o0 = { (_Float16)(a.x * s), (_Float16)(a.y * s), (_Float16)(a.z * s), (_Float16)0.f };
    h4 o1 = { (_Float16)(a.w * s), (_Float16)(b.x * s), (_Float16)(b.y * s), (_Float16)0.f };
    h4 o2 = { (_Float16)(b.z * s), (_Float16)(b.w * s), (_Float16)(c.x * s), (_Float16)0.f };
    h4 o3 = { (_Float16)(c.y * s), (_Float16)(c.z * s), (_Float16)(c.w * s), (_Float16)0.f };
    dst[4 * t + 0] = o0;
    dst[4 * t + 1] = o1;
    dst[4 * t + 2] = o2;
    dst[4 * t + 3] = o3;
}

// ---------- warp step: fp16 field -> fp16 field (or f32 AoS on final) ----------
template <bool AOS_OUT>
__global__ __launch_bounds__(256) void step_k(const h4* __restrict__ src,
                                              h4* __restrict__ dst,
                                              float* __restrict__ daos) {
    const int idx = blockIdx.x * blockDim.x + threadIdx.x;
    const int x = idx & 127;
    const int y = (idx >> 7) & 127;
    const int z = (idx >> 14) & 127;
    const int bb = idx & M_;             // batch base (bit 21)

    const h4 c = src[idx];               // coalesced 8B center read
    const float v0 = (float)c[0];        // D (z) displacement
    const float v1 = (float)c[1];        // H (y)
    const float v2 = (float)c[2];        // W (x)

    const float cz = fminf(fmaxf((float)z + v0, 0.0f), 127.0f);
    const float cy = fminf(fmaxf((float)y + v1, 0.0f), 127.0f);
    const float cx = fminf(fmaxf((float)x + v2, 0.0f), 127.0f);

    const float fz = floorf(cz), fy = floorf(cy), fx = floorf(cx);
    const float wz = cz - fz, wy = cy - fy, wx = cx - fx;
    const int i0z = (int)fz, i0y = (int)fy, i0x = (int)fx;
    const int i1z = min(i0z + 1, 127);
    const int i1y = min(i0y + 1, 127);
    const float wz0 = 1.0f - wz, wy0 = 1.0f - wy, wx0 = 1.0f - wx;
    // x-pair handled by one 16B load at i0x: when i0x==127, cx==127 so wx==0
    // and the (garbage, finite) second voxel gets weight exactly 0.

    float o0 = 0.0f, o1 = 0.0f, o2 = 0.0f;
    #pragma unroll
    for (int b0 = 0; b0 < 2; ++b0) {
        const int   iz  = (b0 ? i1z : i0z) << 14;
        const float wwz = b0 ? wz : wz0;
        #pragma unroll
        for (int b1 = 0; b1 < 2; ++b1) {
            const int   iy  = (b1 ? i1y : i0y) << 7;
            const float w01 = wwz * (b1 ? wy : wy0);
            const H8U* p = (const H8U*)(src + (bb + (iz | iy) + i0x));
            const h8 q = p->v;           // one dwordx4: corners (i0x, i0x+1)
            const float wa = w01 * wx0, wb = w01 * wx;
            o0 += wa * (float)q[0] + wb * (float)q[4];
            o1 += wa * (float)q[1] + wb * (float)q[5];
            o2 += wa * (float)q[2] + wb * (float)q[6];
        }
    }

    const float r0 = v0 + o0, r1 = v1 + o1, r2 = v2 + o2;
    if (AOS_OUT) {
        float* d = daos + (size_t)idx * 3;
        d[0] = r0; d[1] = r1; d[2] = r2;
    } else {
        h4 r = { (_Float16)r0, (_Float16)r1, (_Float16)r2, (_Float16)0.f };
        dst[idx] = r;
    }
}

extern "C" void kernel_launch(void* const* d_in, const int* in_sizes, int n_in,
                              void* d_out, int out_size, void* d_ws, size_t ws_size,
                              hipStream_t stream) {
    const float* dvf = (const float*)d_in[0];
    float* out = (float*)d_out;

    // Two fp16 field buffers (NVOX * 8B = 33.5MB each):
    //   B = front of d_ws, A = front of d_out (dead before the final f32 write).
    h4* B = (h4*)d_ws;
    h4* A = (h4*)d_out;

    const dim3 blk(256);
    const dim3 grd(NVOX / 256);
    const dim3 grd4(NVOX / 4 / 256);

    t_kernel<<<grd4, blk, 0, stream>>>(dvf, B);                       // pack+scale
    step_k<false><<<grd, blk, 0, stream>>>(B, A, nullptr);            // s1
    step_k<false><<<grd, blk, 0, stream>>>(A, B, nullptr);            // s2
    step_k<false><<<grd, blk, 0, stream>>>(B, A, nullptr);            // s3
    step_k<false><<<grd, blk, 0, stream>>>(A, B, nullptr);            // s4
    step_k<false><<<grd, blk, 0, stream>>>(B, A, nullptr);            // s5
    step_k<false><<<grd, blk, 0, stream>>>(A, B, nullptr);            // s6
    step_k<true> <<<grd, blk, 0, stream>>>(B, nullptr, out);          // s7 -> f32 AoS
}

// Round 5
// 167.504 us; speedup vs baseline: 2.2711x; 1.0574x over previous
//
#include <hip/hip_runtime.h>

// IntDVF: scaling-and-squaring integration of a stationary velocity field.
// ddf = dvf / 2^7; repeat 7x: ddf = ddf + trilerp(ddf, grid + ddf)
// Volume: (B=2, D=128, H=128, W=128, C=3) float32, coords clamped to [0,127].
//
// Intermediates: fp16 padded to 8B/voxel so each row's x-pair (2 corners x 3ch)
// is ONE 16B dwordx4 gather -> 4 gather instrs/voxel (R3: 24.5us/step).
// R5 = R4 with the ping-pong parity FIXED: step1 (pack folded) writes A so the
// final step reads B (=ws) and writes f32 AoS into d_out without aliasing.
// XCD z-slab swizzle: each XCD gets a contiguous ~0.5M-voxel slab so its
// gather halo (~5.5MB) mostly lives in its own 4MB L2.

#define M_   (1 << 21)          // 128^3 voxels per batch
#define NVOX (1 << 22)          // 2 batches
#define NBLK (NVOX / 256)       // 16384 blocks, %8 == 0

typedef _Float16 h4 __attribute__((ext_vector_type(4)));
typedef _Float16 h8 __attribute__((ext_vector_type(8)));
struct __attribute__((packed, aligned(8))) H8U { h8 v; };   // 16B load, 8B-aligned

// bijective block swizzle: XCD k (round-robin over blockIdx) gets the
// contiguous work-chunk [k*NBLK/8, (k+1)*NBLK/8)
__device__ __forceinline__ int swz_voxel() {
    const int wb = ((blockIdx.x & 7) * (NBLK / 8)) + (blockIdx.x >> 3);
    return wb * 256 + threadIdx.x;
}

// MODE 0: f32 AoS dvf -> fp16 field (step 1, scale folded)
// MODE 1: fp16 -> fp16
// MODE 2: fp16 -> f32 AoS (final step)
template <int MODE>
__global__ __launch_bounds__(256) void step_k(const float* __restrict__ srcf,
                                              const h4* __restrict__ src,
                                              h4* __restrict__ dst,
                                              float* __restrict__ daos) {
    const int idx = swz_voxel();
    const int x = idx & 127;
    const int y = (idx >> 7) & 127;
    const int z = (idx >> 14) & 127;
    const int bb = idx & M_;             // batch base (bit 21)

    const float scale = (MODE == 0) ? (1.0f / 128.0f) : 1.0f;

    float v0, v1, v2;
    if (MODE == 0) {
        const float* p = srcf + (size_t)idx * 3;
        v0 = p[0] * scale; v1 = p[1] * scale; v2 = p[2] * scale;
    } else {
        const h4 c = src[idx];           // coalesced 8B center read
        v0 = (float)c[0]; v1 = (float)c[1]; v2 = (float)c[2];
    }

    const float cz = fminf(fmaxf((float)z + v0, 0.0f), 127.0f);
    const float cy = fminf(fmaxf((float)y + v1, 0.0f), 127.0f);
    const float cx = fminf(fmaxf((float)x + v2, 0.0f), 127.0f);

    const float fz = floorf(cz), fy = floorf(cy), fx = floorf(cx);
    const float wz = cz - fz, wy = cy - fy, wx = cx - fx;
    const int i0z = (int)fz, i0y = (int)fy, i0x = (int)fx;
    const int i1z = min(i0z + 1, 127);
    const int i1y = min(i0y + 1, 127);
    const float wz0 = 1.0f - wz, wy0 = 1.0f - wy, wx0 = 1.0f - wx;

    float o0 = 0.0f, o1 = 0.0f, o2 = 0.0f;
    #pragma unroll
    for (int b0 = 0; b0 < 2; ++b0) {
        const int   iz  = (b0 ? i1z : i0z) << 14;
        const float wwz = b0 ? wz : wz0;
        #pragma unroll
        for (int b1 = 0; b1 < 2; ++b1) {
            const int   iy  = (b1 ? i1y : i0y) << 7;
            const float w01 = wwz * (b1 ? wy : wy0);
            if (MODE == 0) {
                // f32 AoS source: two dwordx3 gathers (x0, x1)
                const int i1x = min(i0x + 1, 127);
                const float* qa = srcf + (size_t)(bb + (iz | iy) + i0x) * 3;
                const float* qb = srcf + (size_t)(bb + (iz | iy) + i1x) * 3;
                const float wa = w01 * wx0, wb = w01 * wx;
                o0 += wa * qa[0] + wb * qb[0];
                o1 += wa * qa[1] + wb * qb[1];
                o2 += wa * qa[2] + wb * qb[2];
            } else {
                // fp16 source: one 16B load covers the x-pair (i0x, i0x+1).
                // When i0x==127, cx==127 so wx==0 and the garbage voxel gets
                // weight exactly 0 (values are finite fp16 from our own field
                // or the 0xAA poison pattern, both finite).
                const H8U* p = (const H8U*)(src + (bb + (iz | iy) + i0x));
                const h8 q = p->v;
                const float wa = w01 * wx0, wb = w01 * wx;
                o0 += wa * (float)q[0] + wb * (float)q[4];
                o1 += wa * (float)q[1] + wb * (float)q[5];
                o2 += wa * (float)q[2] + wb * (float)q[6];
            }
        }
    }

    const float r0 = v0 + o0 * scale, r1 = v1 + o1 * scale, r2 = v2 + o2 * scale;
    if (MODE == 2) {
        float* d = daos + (size_t)idx * 3;
        d[0] = r0; d[1] = r1; d[2] = r2;
    } else {
        h4 r = { (_Float16)r0, (_Float16)r1, (_Float16)r2, (_Float16)0.f };
        dst[idx] = r;
    }
}

extern "C" void kernel_launch(void* const* d_in, const int* in_sizes, int n_in,
                              void* d_out, int out_size, void* d_ws, size_t ws_size,
                              hipStream_t stream) {
    const float* dvf = (const float*)d_in[0];
    float* out = (float*)d_out;

    // Two fp16 field buffers (NVOX * 8B = 33.5MB each):
    //   A = front of d_out (dead before the final f32 write), B = front of d_ws.
    // Parity: s1->A, s2 A->B, s3 B->A, s4 A->B, s5 B->A, s6 A->B, s7 B->out.
    // Final step reads B (ws) and writes d_out -- no aliasing.
    h4* A = (h4*)d_out;
    h4* B = (h4*)d_ws;

    const dim3 blk(256);
    const dim3 grd(NBLK);

    step_k<0><<<grd, blk, 0, stream>>>(dvf, nullptr, A, nullptr);     // s1 (+scale+pack)
    step_k<1><<<grd, blk, 0, stream>>>(nullptr, A, B, nullptr);       // s2
    step_k<1><<<grd, blk, 0, stream>>>(nullptr, B, A, nullptr);       // s3
    step_k<1><<<grd, blk, 0, stream>>>(nullptr, A, B, nullptr);       // s4
    step_k<1><<<grd, blk, 0, stream>>>(nullptr, B, A, nullptr);       // s5
    step_k<1><<<grd, blk, 0, stream>>>(nullptr, A, B, nullptr);       // s6
    step_k<2><<<grd, blk, 0, stream>>>(nullptr, B, nullptr, out);     // s7 -> f32 AoS
}